// Round 6
// baseline (467.876 us; speedup 1.0000x reference)
//
#include <hip/hip_runtime.h>
#include <math.h>

#define BB 16
#define CC 256
#define HH 128
#define WW 128
#define HW (HH*WW)
#define CHW (CC*HW)
#define NQ (BB*CHW)          // 67,108,864 quantized elements
#define NI (BB*HW)           // 262,144 per-pixel elements
#define PIX 64               // pixels per block
#define NTHREADS 512
#define FEPS 1e-6f

typedef float f32x4 __attribute__((ext_vector_type(4)));  // native vec for nt-store

// quantize one value; first divide must be IEEE-exact (feeds rintf boundary),
// final step uses precomputed scl = denom/lm1 (post-rounding, <=2ulp vs ref)
__device__ __forceinline__ float quant_one(float x, float fmin, float denom,
                                           float lm1, float scl) {
    float fn = (x - fmin) / denom;
    float rq = rintf(fn * lm1);      // round-half-even like jnp.round
    return rq * scl + fmin;
}

__global__ __launch_bounds__(NTHREADS, 4)
void hafis_fused(const float* __restrict__ feat,
                 const float* __restrict__ w1, const float* __restrict__ b1,
                 const float* __restrict__ w2, const float* __restrict__ b2,
                 const float* __restrict__ l1w, const float* __restrict__ l1b,
                 const float* __restrict__ l2w, const float* __restrict__ l2b,
                 const int*   __restrict__ snr_p,
                 float* __restrict__ out)
{
    // wave-partial stats: [wave][stat][pixel-sub][group]  = 10 KB
    __shared__ float pstat[8][5][4][16];
    __shared__ float4 params[PIX];   // (fmin, denom, lm1, denom/lm1)

    const int t   = threadIdx.x;
    const int bid = blockIdx.x;           // grid = 16*128*2 = 4096
    const int w0  = (bid & 1) * PIX;
    const int h   = (bid >> 1) & (HH - 1);
    const int b   = bid >> 8;

    const int g = t & 15;                 // pixel quad: pixels 4g..4g+3
    const int r = t >> 4;                 // channel row 0..31 (c = i*32 + r)

    const size_t tilebase = (size_t)b * CHW + (size_t)h * WW + w0;
    const float* src = feat + tilebase + (size_t)r * HW + 4 * g;

    // ---- phase 1: load 8 float4s into registers, fuse per-pixel stats ----
    float4 d[8];
    float s[4]  = {0.f, 0.f, 0.f, 0.f};
    float ss[4] = {0.f, 0.f, 0.f, 0.f};
    float sa[4] = {0.f, 0.f, 0.f, 0.f};
    float mn[4] = {INFINITY, INFINITY, INFINITY, INFINITY};
    float mx[4] = {-INFINITY, -INFINITY, -INFINITY, -INFINITY};

    #pragma unroll
    for (int i = 0; i < 8; ++i) {
        float4 x = *reinterpret_cast<const float4*>(src + (size_t)i * 32 * HW);
        d[i] = x;
        const float* xs = reinterpret_cast<const float*>(&x);
        #pragma unroll
        for (int j = 0; j < 4; ++j) {
            float v = xs[j];
            s[j]  += v;
            ss[j] += v * v;
            sa[j] += fabsf(v);
            mn[j] = fminf(mn[j], v);
            mx[j] = fmaxf(mx[j], v);
        }
    }

    // ---- intra-wave combine: lanes {l, l^16, l^32, l^48} share pixel quad ----
    #pragma unroll
    for (int j = 0; j < 4; ++j) {
        s[j]  += __shfl_xor(s[j], 16);  s[j]  += __shfl_xor(s[j], 32);
        ss[j] += __shfl_xor(ss[j], 16); ss[j] += __shfl_xor(ss[j], 32);
        sa[j] += __shfl_xor(sa[j], 16); sa[j] += __shfl_xor(sa[j], 32);
        mn[j] = fminf(mn[j], __shfl_xor(mn[j], 16));
        mn[j] = fminf(mn[j], __shfl_xor(mn[j], 32));
        mx[j] = fmaxf(mx[j], __shfl_xor(mx[j], 16));
        mx[j] = fmaxf(mx[j], __shfl_xor(mx[j], 32));
    }

    const int lane = t & 63;
    const int wv   = t >> 6;
    if (lane < 16) {
        #pragma unroll
        for (int j = 0; j < 4; ++j) {
            pstat[wv][0][j][lane] = s[j];
            pstat[wv][1][j][lane] = ss[j];
            pstat[wv][2][j][lane] = sa[j];
            pstat[wv][3][j][lane] = mn[j];
            pstat[wv][4][j][lane] = mx[j];
        }
    }
    __syncthreads();

    // ---- phase 2: combine 8 wave-partials + per-pixel MLPs (64 threads) ----
    if (t < PIX) {
        const int p  = t;
        const int gg = p >> 2;
        const int jj = p & 3;
        float S = 0.f, SS = 0.f, SA = 0.f, MN = INFINITY, MX = -INFINITY;
        #pragma unroll
        for (int w = 0; w < 8; ++w) {
            S  += pstat[w][0][jj][gg];
            SS += pstat[w][1][jj][gg];
            SA += pstat[w][2][jj][gg];
            MN = fminf(MN, pstat[w][3][jj][gg]);
            MX = fmaxf(MX, pstat[w][4][jj][gg]);
        }
        float mean_sq  = SS * (1.f / CC);
        float mean_abs = SA * (1.f / CC);
        float mag  = sqrtf(SS) * (1.f / 16.f);
        float var  = (SS - S * S * (1.f / CC)) * (1.f / (CC - 1));
        float stdv = sqrtf(var);
        float varn = var  / (mean_sq  + FEPS);
        float stdn = stdv / (mean_abs + FEPS);
        mag  = fminf(fmaxf(mag,  0.f), 1.f);
        varn = fminf(fmaxf(varn, 0.f), 1.f);
        stdn = fminf(fmaxf(stdn, 0.f), 1.f);

        // conv fusion 3 -> 16 -> 1 (1x1 convs)
        float acc = b2[0];
        #pragma unroll
        for (int o = 0; o < 16; ++o) {
            float hh2 = w1[o * 3 + 0] * mag + w1[o * 3 + 1] * varn
                      + w1[o * 3 + 2] * stdn + b1[o];
            hh2 = fmaxf(hh2, 0.f);
            acc += w2[o] * hh2;
        }
        float imp = 1.f / (1.f + expf(-acc));

        // bit MLP 3 -> 32 -> 1
        int iv = snr_p[0];
        float snr = (iv > -1000 && iv < 1000) ? (float)iv : __int_as_float(iv);
        float snrn = snr * (1.f / 30.f);
        float acc2 = l2b[0];
        #pragma unroll
        for (int o = 0; o < 32; ++o) {
            float z = l1w[o * 3 + 0] * imp + l1w[o * 3 + 1] * snrn
                    + l1w[o * 3 + 2] * 0.5f + l1b[o];
            z = fmaxf(z, 0.f);
            acc2 += l2w[o] * z;
        }
        float bsig = 1.f / (1.f + expf(-acc2));
        float bits = 4.f + bsig * 8.f;
        float lm1  = exp2f(bits) - 1.f;
        float denom = MX - MN + FEPS;
        float scl   = denom / lm1;       // exact once per pixel

        params[p] = make_float4(MN, denom, lm1, scl);

        size_t pix = (size_t)b * HW + (size_t)h * WW + w0 + p;
        out[NQ + pix]      = imp;
        out[NQ + NI + pix] = bits;
    }
    __syncthreads();

    // ---- phase 3: quantize from registers, nontemporal float4 stores ----
    float4 pr0 = params[4 * g + 0];
    float4 pr1 = params[4 * g + 1];
    float4 pr2 = params[4 * g + 2];
    float4 pr3 = params[4 * g + 3];
    float* op = out + tilebase + (size_t)r * HW + 4 * g;
    #pragma unroll
    for (int i = 0; i < 8; ++i) {
        float4 x = d[i];
        f32x4 q;
        q.x = quant_one(x.x, pr0.x, pr0.y, pr0.z, pr0.w);
        q.y = quant_one(x.y, pr1.x, pr1.y, pr1.z, pr1.w);
        q.z = quant_one(x.z, pr2.x, pr2.y, pr2.z, pr2.w);
        q.w = quant_one(x.w, pr3.x, pr3.y, pr3.z, pr3.w);
        __builtin_nontemporal_store(q, reinterpret_cast<f32x4*>(op + (size_t)i * 32 * HW));
    }
}

extern "C" void kernel_launch(void* const* d_in, const int* in_sizes, int n_in,
                              void* d_out, int out_size, void* d_ws, size_t ws_size,
                              hipStream_t stream) {
    const float* feat = (const float*)d_in[0];
    const float* w1   = (const float*)d_in[1];
    const float* b1   = (const float*)d_in[2];
    const float* w2   = (const float*)d_in[3];
    const float* b2   = (const float*)d_in[4];
    const float* l1w  = (const float*)d_in[5];
    const float* l1b  = (const float*)d_in[6];
    const float* l2w  = (const float*)d_in[7];
    const float* l2b  = (const float*)d_in[8];
    const int*   snr  = (const int*)d_in[9];
    float* out = (float*)d_out;

    dim3 grid(BB * HH * (WW / PIX));   // 4096
    dim3 block(NTHREADS);
    hipLaunchKernelGGL(hafis_fused, grid, block, 0, stream,
                       feat, w1, b1, w2, b2, l1w, l1b, l2w, l2b, snr, out);
}